// Round 1
// baseline (16068.079 us; speedup 1.0000x reference)
//
#include <hip/hip_runtime.h>
#include <math.h>

#define BB 8
#define TT 4096
#define DD 512
#define CCH 64      // scan chunk
#define NCH 64
#define CPP 256     // phase-3 chunk
#define NPP 16
constexpr float LRF = 0.01f;

// ---------------- workspace layout (floats) ----------------
// A   : [T][D]          mean of x over batch
// CU  : [T][D]          c_s * u_s
// G   : [NCH][64][64]   per-chunk Gram of A (G[k][s][t] = a_s . a_t)
// BV  : [64][D]         per-chunk b vectors (reused)
// W   : [D][D]          running W_base + W_c
// WS  : [NPP][D][D]     W snapshots at t = 256*p
// S   : [NPP][2048][256] attention scores
#define OFF_A  0
#define OFF_CU 2097152
#define OFF_G  4194304
#define OFF_BV 4456448
#define OFF_W  4489216
#define OFF_WS 4751360
#define OFF_S  8945664
// total = 17334272 floats = 69.3 MB

__global__ void tm_mean(const float* __restrict__ x, float* __restrict__ a) {
    int idx = blockIdx.x * 256 + threadIdx.x;   // t*D + d
    float s = 0.f;
#pragma unroll
    for (int b = 0; b < BB; ++b) s += x[b * (TT * DD) + idx];
    a[idx] = s * 0.125f;
}

__global__ void tm_init(const float* __restrict__ wb, const float* __restrict__ wc,
                        float* __restrict__ W, float* __restrict__ Wsnap) {
    int idx = blockIdx.x * 256 + threadIdx.x;
    float v = wb[idx] + wc[idx];
    W[idx] = v;
    Wsnap[idx] = v;   // snapshot p=0 (t=0)
}

// per-chunk 64x64 Gram of A; one block per chunk
__global__ __launch_bounds__(256) void tm_gram(const float* __restrict__ a, float* __restrict__ Gt) {
    __shared__ float al[64 * 129];
    int k = blockIdx.x, tid = threadIdx.x;
    int s0 = (tid >> 4) * 4, t0 = (tid & 15) * 4;
    float acc[4][4] = {};
    for (int kt = 0; kt < 4; ++kt) {
        __syncthreads();
        for (int l = tid; l < 64 * 32; l += 256) {
            int r = l >> 5, c4 = (l & 31) * 4;
            float4 v = *(const float4*)&a[(k * 64 + r) * DD + kt * 128 + c4];
            al[r * 129 + c4] = v.x; al[r * 129 + c4 + 1] = v.y;
            al[r * 129 + c4 + 2] = v.z; al[r * 129 + c4 + 3] = v.w;
        }
        __syncthreads();
        for (int j = 0; j < 128; ++j) {
            float as[4], at[4];
#pragma unroll
            for (int i = 0; i < 4; ++i) { as[i] = al[(s0 + i) * 129 + j]; at[i] = al[(t0 + i) * 129 + j]; }
#pragma unroll
            for (int i = 0; i < 4; ++i)
#pragma unroll
                for (int jj = 0; jj < 4; ++jj) acc[i][jj] += as[i] * at[jj];
        }
    }
#pragma unroll
    for (int i = 0; i < 4; ++i)
#pragma unroll
        for (int jj = 0; jj < 4; ++jj)
            Gt[k * 4096 + (s0 + i) * 64 + (t0 + jj)] = acc[i][jj];
}

// bv[t][i] = a[T0+t][i] - sum_j W[i][j] a[T0+t][j]; block = 8 rows of W, all 64 t
__global__ __launch_bounds__(512) void tm_bvec(const float* __restrict__ a, const float* __restrict__ W,
                                               float* __restrict__ bv, int T0) {
    __shared__ float al[64 * 129];
    __shared__ float wl[8 * 129];
    int tid = threadIdx.x;
    int t = tid & 63, ip = tid >> 6;            // ip 0..7
    int i = blockIdx.x * 8 + ip;
    float acc = 0.f;
    for (int kt = 0; kt < 4; ++kt) {
        __syncthreads();
        for (int l = tid; l < 64 * 32; l += 512) {
            int r = l >> 5, c4 = (l & 31) * 4;
            float4 v = *(const float4*)&a[(T0 + r) * DD + kt * 128 + c4];
            al[r * 129 + c4] = v.x; al[r * 129 + c4 + 1] = v.y;
            al[r * 129 + c4 + 2] = v.z; al[r * 129 + c4 + 3] = v.w;
        }
        for (int l = tid; l < 8 * 32; l += 512) {
            int r = l >> 5, c4 = (l & 31) * 4;
            float4 v = *(const float4*)&W[(blockIdx.x * 8 + r) * DD + kt * 128 + c4];
            wl[r * 129 + c4] = v.x; wl[r * 129 + c4 + 1] = v.y;
            wl[r * 129 + c4 + 2] = v.z; wl[r * 129 + c4 + 3] = v.w;
        }
        __syncthreads();
#pragma unroll 4
        for (int j = 0; j < 128; ++j) acc += al[t * 129 + j] * wl[ip * 129 + j];
    }
    bv[t * DD + i] = a[(T0 + t) * DD + i] - acc;
}

// sequential intra-chunk scan; ONE block, 512 threads (thread = dim d)
__global__ __launch_bounds__(512) void tm_scan(const float* __restrict__ bv, const float* __restrict__ Gt,
                                               float* __restrict__ cu, int k) {
    __shared__ float part[2][8];
    int tid = threadIdx.x;
    int wid = tid >> 6, lane = tid & 63;
    float acc[64];
#pragma unroll
    for (int t = 0; t < 64; ++t) acc[t] = bv[t * DD + tid];
    const float* gk = Gt + k * 4096;
    int T0 = k * 64;
#pragma unroll
    for (int s = 0; s < 64; ++s) {
        float u = acc[s];
        float v = u * u;
#pragma unroll
        for (int off = 32; off > 0; off >>= 1) v += __shfl_xor(v, off, 64);
        if (lane == 0) part[s & 1][wid] = v;
        __syncthreads();
        float n2u = 0.f;
#pragma unroll
        for (int w2 = 0; w2 < 8; ++w2) n2u += part[s & 1][w2];
        float n2 = n2u * gk[s * 64 + s];                     // ||u||^2 * ||a||^2
        float cs = (n2 > 0.25f) ? 0.5f * rsqrtf(n2) : 1.0f;  // min(1, CLIP/n)
        cu[(T0 + s) * DD + tid] = cs * u;
        float w = (LRF * cs) * u;
#pragma unroll
        for (int t = s + 1; t < 64; ++t) acc[t] -= gk[s * 64 + t] * w;
    }
}

// W += LR * sum_r cu[r] (x) a[r]  (rank-64 update); optional snapshot / final output
__global__ void tm_wupd(const float* __restrict__ a, const float* __restrict__ cu,
                        float* __restrict__ W, float* __restrict__ Wsnap,
                        const float* __restrict__ wb, float* __restrict__ outW,
                        int kprev, int snap_p, int is_final) {
    int idx = blockIdx.x * 256 + threadIdx.x;
    int i = idx >> 9, j = idx & 511;
    const float* cb = cu + kprev * 64 * DD;
    const float* ab = a + kprev * 64 * DD;
    float s = 0.f;
#pragma unroll
    for (int r = 0; r < 64; ++r) s += cb[r * DD + i] * ab[r * DD + j];
    float w = W[idx] + LRF * s;
    W[idx] = w;
    if (snap_p >= 0) Wsnap[snap_p * DD * DD + idx] = w;
    if (is_final) outW[idx] = w - wb[idx];
}

// out[b,t,:] = x[b,t,:] @ Wsnap[p].T   (64x64 tile GEMM, 4x4 micro)
__global__ __launch_bounds__(256) void tm_mem(const float* __restrict__ x, const float* __restrict__ Wsnap,
                                              float* __restrict__ out) {
    __shared__ float al[64 * 65];
    __shared__ float bl[64 * 65];
    int bid = blockIdx.x;
    int p = bid >> 8, rem = bid & 255, rt = rem >> 3, it = rem & 7;
    int tid = threadIdx.x;
    int c0 = (tid & 15) * 4, r0 = (tid >> 4) * 4;
    const float* Wp = Wsnap + p * DD * DD;
    float acc[4][4] = {};
    for (int kt = 0; kt < 8; ++kt) {
        if (kt) __syncthreads();
        for (int l = tid; l < 64 * 16; l += 256) {
            int r = l >> 4, c4 = (l & 15) * 4;
            int rloc = rt * 64 + r;
            int grow = ((rloc >> 8) * TT) + p * 256 + (rloc & 255);
            float4 v = *(const float4*)&x[grow * DD + kt * 64 + c4];
            al[r * 65 + c4] = v.x; al[r * 65 + c4 + 1] = v.y;
            al[r * 65 + c4 + 2] = v.z; al[r * 65 + c4 + 3] = v.w;
            float4 u = *(const float4*)&Wp[(it * 64 + r) * DD + kt * 64 + c4];
            bl[r * 65 + c4] = u.x; bl[r * 65 + c4 + 1] = u.y;
            bl[r * 65 + c4 + 2] = u.z; bl[r * 65 + c4 + 3] = u.w;
        }
        __syncthreads();
        for (int kk = 0; kk < 64; ++kk) {
            float af[4], bf[4];
#pragma unroll
            for (int q = 0; q < 4; ++q) { af[q] = al[(r0 + q) * 65 + kk]; bf[q] = bl[(c0 + q) * 65 + kk]; }
#pragma unroll
            for (int q = 0; q < 4; ++q)
#pragma unroll
                for (int w2 = 0; w2 < 4; ++w2) acc[q][w2] += af[q] * bf[w2];
        }
    }
#pragma unroll
    for (int q = 0; q < 4; ++q) {
        int rloc = rt * 64 + r0 + q;
        int grow = ((rloc >> 8) * TT) + p * 256 + (rloc & 255);
        float4 v = make_float4(acc[q][0], acc[q][1], acc[q][2], acc[q][3]);
        *(float4*)&out[grow * DD + it * 64 + c0] = v;
    }
}

// S[p][rloc][s] = x[row] . a[p*256+s]
__global__ __launch_bounds__(256) void tm_score(const float* __restrict__ x, const float* __restrict__ a,
                                                float* __restrict__ S) {
    __shared__ float al[64 * 65];
    __shared__ float bl[64 * 65];
    int bid = blockIdx.x;
    int st = bid & 3, rt = (bid >> 2) & 31, p = bid >> 7;
    int tid = threadIdx.x;
    int c0 = (tid & 15) * 4, r0 = (tid >> 4) * 4;
    float acc[4][4] = {};
    for (int kt = 0; kt < 8; ++kt) {
        if (kt) __syncthreads();
        for (int l = tid; l < 64 * 16; l += 256) {
            int r = l >> 4, c4 = (l & 15) * 4;
            int rloc = rt * 64 + r;
            int grow = ((rloc >> 8) * TT) + p * 256 + (rloc & 255);
            float4 v = *(const float4*)&x[grow * DD + kt * 64 + c4];
            al[r * 65 + c4] = v.x; al[r * 65 + c4 + 1] = v.y;
            al[r * 65 + c4 + 2] = v.z; al[r * 65 + c4 + 3] = v.w;
            float4 u = *(const float4*)&a[(p * 256 + st * 64 + r) * DD + kt * 64 + c4];
            bl[r * 65 + c4] = u.x; bl[r * 65 + c4 + 1] = u.y;
            bl[r * 65 + c4 + 2] = u.z; bl[r * 65 + c4 + 3] = u.w;
        }
        __syncthreads();
        for (int kk = 0; kk < 64; ++kk) {
            float af[4], bf[4];
#pragma unroll
            for (int q = 0; q < 4; ++q) { af[q] = al[(r0 + q) * 65 + kk]; bf[q] = bl[(c0 + q) * 65 + kk]; }
#pragma unroll
            for (int q = 0; q < 4; ++q)
#pragma unroll
                for (int w2 = 0; w2 < 4; ++w2) acc[q][w2] += af[q] * bf[w2];
        }
    }
#pragma unroll
    for (int q = 0; q < 4; ++q) {
        int rloc = rt * 64 + r0 + q;
        float4 v = make_float4(acc[q][0], acc[q][1], acc[q][2], acc[q][3]);
        *(float4*)&S[(p * 2048 + rloc) * 256 + st * 64 + c0] = v;
    }
}

// out[row][i] += LR * sum_{s<tloc} S[p][rloc][s] * cu[p*256+s][i]
__global__ __launch_bounds__(256) void tm_apply(const float* __restrict__ S, const float* __restrict__ cu,
                                                float* __restrict__ out) {
    __shared__ float al[64 * 65];
    __shared__ float bl[64 * 65];
    int bid = blockIdx.x;
    int it = bid & 7, rt = (bid >> 3) & 31, p = bid >> 8;
    int tid = threadIdx.x;
    int c0 = (tid & 15) * 4, r0 = (tid >> 4) * 4;
    float acc[4][4] = {};
    for (int kt = 0; kt < 4; ++kt) {
        if (kt) __syncthreads();
        for (int l = tid; l < 64 * 16; l += 256) {
            int r = l >> 4, c4 = (l & 15) * 4;
            int rloc = rt * 64 + r;
            int tq = rloc & 255;
            float4 v = *(const float4*)&S[(p * 2048 + rloc) * 256 + kt * 64 + c4];
            int sb = kt * 64 + c4;
            al[r * 65 + c4]     = (sb + 0 < tq) ? v.x : 0.f;
            al[r * 65 + c4 + 1] = (sb + 1 < tq) ? v.y : 0.f;
            al[r * 65 + c4 + 2] = (sb + 2 < tq) ? v.z : 0.f;
            al[r * 65 + c4 + 3] = (sb + 3 < tq) ? v.w : 0.f;
            float4 u = *(const float4*)&cu[(p * 256 + kt * 64 + r) * DD + it * 64 + c4];
            bl[r * 65 + c4] = u.x; bl[r * 65 + c4 + 1] = u.y;
            bl[r * 65 + c4 + 2] = u.z; bl[r * 65 + c4 + 3] = u.w;
        }
        __syncthreads();
        for (int kk = 0; kk < 64; ++kk) {
            float af[4], bf[4];
#pragma unroll
            for (int q = 0; q < 4; ++q) { af[q] = al[(r0 + q) * 65 + kk]; bf[q] = bl[kk * 65 + c0 + q]; }
#pragma unroll
            for (int q = 0; q < 4; ++q)
#pragma unroll
                for (int w2 = 0; w2 < 4; ++w2) acc[q][w2] += af[q] * bf[w2];
        }
    }
#pragma unroll
    for (int q = 0; q < 4; ++q) {
        int rloc = rt * 64 + r0 + q;
        int grow = ((rloc >> 8) * TT) + p * 256 + (rloc & 255);
        float4 cur = *(float4*)&out[grow * DD + it * 64 + c0];
        cur.x += LRF * acc[q][0]; cur.y += LRF * acc[q][1];
        cur.z += LRF * acc[q][2]; cur.w += LRF * acc[q][3];
        *(float4*)&out[grow * DD + it * 64 + c0] = cur;
    }
}

// out[row][i] *= sigmoid(x[row] . gate_w[i] + gate_b[i])
__global__ __launch_bounds__(256) void tm_gate(const float* __restrict__ x, const float* __restrict__ gw,
                                               const float* __restrict__ gb, float* __restrict__ out) {
    __shared__ float al[64 * 65];
    __shared__ float bl[64 * 65];
    int bid = blockIdx.x;
    int it = bid & 7, rt = bid >> 3;
    int tid = threadIdx.x;
    int c0 = (tid & 15) * 4, r0 = (tid >> 4) * 4;
    float acc[4][4] = {};
    for (int kt = 0; kt < 8; ++kt) {
        if (kt) __syncthreads();
        for (int l = tid; l < 64 * 16; l += 256) {
            int r = l >> 4, c4 = (l & 15) * 4;
            int grow = rt * 64 + r;
            float4 v = *(const float4*)&x[grow * DD + kt * 64 + c4];
            al[r * 65 + c4] = v.x; al[r * 65 + c4 + 1] = v.y;
            al[r * 65 + c4 + 2] = v.z; al[r * 65 + c4 + 3] = v.w;
            float4 u = *(const float4*)&gw[(it * 64 + r) * DD + kt * 64 + c4];
            bl[r * 65 + c4] = u.x; bl[r * 65 + c4 + 1] = u.y;
            bl[r * 65 + c4 + 2] = u.z; bl[r * 65 + c4 + 3] = u.w;
        }
        __syncthreads();
        for (int kk = 0; kk < 64; ++kk) {
            float af[4], bf[4];
#pragma unroll
            for (int q = 0; q < 4; ++q) { af[q] = al[(r0 + q) * 65 + kk]; bf[q] = bl[(c0 + q) * 65 + kk]; }
#pragma unroll
            for (int q = 0; q < 4; ++q)
#pragma unroll
                for (int w2 = 0; w2 < 4; ++w2) acc[q][w2] += af[q] * bf[w2];
        }
    }
#pragma unroll
    for (int q = 0; q < 4; ++q) {
        int grow = rt * 64 + r0 + q;
        float4 cur = *(float4*)&out[grow * DD + it * 64 + c0];
        float z0 = acc[q][0] + gb[it * 64 + c0 + 0];
        float z1 = acc[q][1] + gb[it * 64 + c0 + 1];
        float z2 = acc[q][2] + gb[it * 64 + c0 + 2];
        float z3 = acc[q][3] + gb[it * 64 + c0 + 3];
        cur.x *= 1.f / (1.f + expf(-z0));
        cur.y *= 1.f / (1.f + expf(-z1));
        cur.z *= 1.f / (1.f + expf(-z2));
        cur.w *= 1.f / (1.f + expf(-z3));
        *(float4*)&out[grow * DD + it * 64 + c0] = cur;
    }
}

extern "C" void kernel_launch(void* const* d_in, const int* in_sizes, int n_in,
                              void* d_out, int out_size, void* d_ws, size_t ws_size,
                              hipStream_t stream) {
    const float* x   = (const float*)d_in[0];
    const float* Wc0 = (const float*)d_in[1];
    const float* Wb  = (const float*)d_in[2];
    const float* gw  = (const float*)d_in[3];
    const float* gb  = (const float*)d_in[4];
    float* out  = (float*)d_out;
    float* outW = out + BB * TT * DD;   // 16777216

    float* ws = (float*)d_ws;
    float* A  = ws + OFF_A;
    float* CU = ws + OFF_CU;
    float* G  = ws + OFF_G;
    float* BV = ws + OFF_BV;
    float* W  = ws + OFF_W;
    float* WS = ws + OFF_WS;
    float* S  = ws + OFF_S;

    tm_mean<<<(TT * DD) / 256, 256, 0, stream>>>(x, A);
    tm_init<<<(DD * DD) / 256, 256, 0, stream>>>(Wb, Wc0, W, WS);
    tm_gram<<<NCH, 256, 0, stream>>>(A, G);

    for (int k = 0; k < NCH; ++k) {
        if (k > 0)
            tm_wupd<<<(DD * DD) / 256, 256, 0, stream>>>(A, CU, W, WS, Wb, outW,
                                                         k - 1, (k % 4 == 0) ? (k / 4) : -1, 0);
        tm_bvec<<<64, 512, 0, stream>>>(A, W, BV, k * 64);
        tm_scan<<<1, 512, 0, stream>>>(BV, G, CU, k);
    }
    tm_wupd<<<(DD * DD) / 256, 256, 0, stream>>>(A, CU, W, WS, Wb, outW, NCH - 1, -1, 1);

    tm_mem<<<NPP * 256, 256, 0, stream>>>(x, WS, out);
    tm_score<<<NPP * 128, 256, 0, stream>>>(x, A, S);
    tm_apply<<<NPP * 256, 256, 0, stream>>>(S, CU, out);
    tm_gate<<<512 * 8, 256, 0, stream>>>(x, gw, gb, out);
}

// Round 2
// 8128.353 us; speedup vs baseline: 1.9768x; 1.9768x over previous
//
#include <hip/hip_runtime.h>
#include <math.h>

#define BB 8
#define TT 4096
#define DD 512
constexpr float LRF = 0.01f;

// ---------------- workspace layout (floats) ----------------
// A  : [4096][512]        mean of x over batch
// CU : [4096][512]        c_s * u_s
// G  : [16][256][256]     per-superchunk Gram of A
// P  : [256][512]         A_sc - A_sc @ W(p)^T   (reused per superchunk)
// BV : [64][512]          corrected b vectors for current chunk
// W  : [512][512]         running W_base + W_c
// WS : [16][512][512]     W snapshots at t = 256*p
// S  : [16][2048][256]    attention scores
#define OFF_A  0
#define OFF_CU 2097152
#define OFF_G  4194304
#define OFF_P  5242880
#define OFF_BV 5373952
#define OFF_W  5406720
#define OFF_WS 5668864
#define OFF_S  9863168
// total = 18251776 floats = 73.0 MB

__global__ void tm_mean(const float* __restrict__ x, float* __restrict__ a) {
    int idx = blockIdx.x * 256 + threadIdx.x;   // t*D + d
    float s = 0.f;
#pragma unroll
    for (int b = 0; b < BB; ++b) s += x[b * (TT * DD) + idx];
    a[idx] = s * 0.125f;
}

__global__ void tm_init(const float* __restrict__ wb, const float* __restrict__ wc,
                        float* __restrict__ W, float* __restrict__ Wsnap) {
    int idx = blockIdx.x * 256 + threadIdx.x;
    float v = wb[idx] + wc[idx];
    W[idx] = v;
    Wsnap[idx] = v;   // snapshot p=0 (t=0)
}

// full Gram per superchunk: G[p][s][t] = a_{p*256+s} . a_{p*256+t}
// grid 256: block = p*16 + ts*4 + tt, computes 64x64 tile
__global__ __launch_bounds__(256) void tm_gram(const float* __restrict__ a, float* __restrict__ G) {
    __shared__ float sl[64 * 65];
    __shared__ float tl[64 * 65];
    int bid = blockIdx.x;
    int p = bid >> 4, ts = (bid >> 2) & 3, tt = bid & 3;
    int tid = threadIdx.x;
    int c0 = (tid & 15) * 4, r0 = (tid >> 4) * 4;
    float acc[4][4] = {};
    for (int kt = 0; kt < 8; ++kt) {
        if (kt) __syncthreads();
        for (int l = tid; l < 64 * 16; l += 256) {
            int r = l >> 4, c4 = (l & 15) * 4;
            float4 v = *(const float4*)&a[(p * 256 + ts * 64 + r) * DD + kt * 64 + c4];
            sl[r * 65 + c4] = v.x; sl[r * 65 + c4 + 1] = v.y;
            sl[r * 65 + c4 + 2] = v.z; sl[r * 65 + c4 + 3] = v.w;
            float4 u = *(const float4*)&a[(p * 256 + tt * 64 + r) * DD + kt * 64 + c4];
            tl[r * 65 + c4] = u.x; tl[r * 65 + c4 + 1] = u.y;
            tl[r * 65 + c4 + 2] = u.z; tl[r * 65 + c4 + 3] = u.w;
        }
        __syncthreads();
        for (int kk = 0; kk < 64; ++kk) {
            float as[4], at[4];
#pragma unroll
            for (int q = 0; q < 4; ++q) { as[q] = sl[(r0 + q) * 65 + kk]; at[q] = tl[(c0 + q) * 65 + kk]; }
#pragma unroll
            for (int q = 0; q < 4; ++q)
#pragma unroll
                for (int w2 = 0; w2 < 4; ++w2) acc[q][w2] += as[q] * at[w2];
        }
    }
#pragma unroll
    for (int q = 0; q < 4; ++q) {
        float4 v = make_float4(acc[q][0], acc[q][1], acc[q][2], acc[q][3]);
        *(float4*)&G[p * 65536 + (ts * 64 + r0 + q) * 256 + tt * 64 + c0] = v;
    }
}

// P[t][i] = a[p*256+t][i] - sum_j W[i][j] a[p*256+t][j];  grid 32 (bt 0..3, bi 0..7)
__global__ __launch_bounds__(256) void tm_P(const float* __restrict__ a, const float* __restrict__ W,
                                            float* __restrict__ P, int p) {
    __shared__ float al[64 * 65];
    __shared__ float wl[64 * 65];
    int bid = blockIdx.x;
    int bt = bid & 3, bi = bid >> 2;
    int tid = threadIdx.x;
    int c0 = (tid & 15) * 4, r0 = (tid >> 4) * 4;
    float acc[4][4] = {};
    for (int kt = 0; kt < 8; ++kt) {
        if (kt) __syncthreads();
        for (int l = tid; l < 64 * 16; l += 256) {
            int r = l >> 4, c4 = (l & 15) * 4;
            float4 v = *(const float4*)&a[(p * 256 + bt * 64 + r) * DD + kt * 64 + c4];
            al[r * 65 + c4] = v.x; al[r * 65 + c4 + 1] = v.y;
            al[r * 65 + c4 + 2] = v.z; al[r * 65 + c4 + 3] = v.w;
            float4 u = *(const float4*)&W[(bi * 64 + r) * DD + kt * 64 + c4];
            wl[r * 65 + c4] = u.x; wl[r * 65 + c4 + 1] = u.y;
            wl[r * 65 + c4 + 2] = u.z; wl[r * 65 + c4 + 3] = u.w;
        }
        __syncthreads();
        for (int kk = 0; kk < 64; ++kk) {
            float af[4], bf[4];
#pragma unroll
            for (int q = 0; q < 4; ++q) { af[q] = al[(r0 + q) * 65 + kk]; bf[q] = wl[(c0 + q) * 65 + kk]; }
#pragma unroll
            for (int q = 0; q < 4; ++q)
#pragma unroll
                for (int w2 = 0; w2 < 4; ++w2) acc[q][w2] += af[q] * bf[w2];
        }
    }
#pragma unroll
    for (int q = 0; q < 4; ++q) {
        float4 av = *(const float4*)&a[(p * 256 + bt * 64 + r0 + q) * DD + bi * 64 + c0];
        float4 v = make_float4(av.x - acc[q][0], av.y - acc[q][1],
                               av.z - acc[q][2], av.w - acc[q][3]);
        *(float4*)&P[(bt * 64 + r0 + q) * DD + bi * 64 + c0] = v;
    }
}

// bv[t][d] = P[j*64+t][d] - LR * sum_{s<j*64} G[p][s][j*64+t] * CU[p*256+s][d]
// grid 8 (d-tiles); j=0 degenerates to copy
__global__ __launch_bounds__(256) void tm_corr(const float* __restrict__ P, const float* __restrict__ G,
                                               const float* __restrict__ CU, float* __restrict__ bv,
                                               int p, int j) {
    __shared__ float gsl[64 * 65];
    __shared__ float cul[64 * 65];
    int bd = blockIdx.x;
    int tid = threadIdx.x;
    int c0 = (tid & 15) * 4, r0 = (tid >> 4) * 4;   // r -> t, c -> d
    const float* Gp = G + p * 65536;
    float acc[4][4] = {};
    for (int kb = 0; kb < j * 64; kb += 64) {
        if (kb) __syncthreads();
        for (int l = tid; l < 64 * 16; l += 256) {
            int r = l >> 4, c4 = (l & 15) * 4;
            float4 v = *(const float4*)&Gp[(kb + r) * 256 + j * 64 + c4];
            gsl[r * 65 + c4] = v.x; gsl[r * 65 + c4 + 1] = v.y;
            gsl[r * 65 + c4 + 2] = v.z; gsl[r * 65 + c4 + 3] = v.w;
            float4 u = *(const float4*)&CU[(p * 256 + kb + r) * DD + bd * 64 + c4];
            cul[r * 65 + c4] = u.x; cul[r * 65 + c4 + 1] = u.y;
            cul[r * 65 + c4 + 2] = u.z; cul[r * 65 + c4 + 3] = u.w;
        }
        __syncthreads();
        for (int kk = 0; kk < 64; ++kk) {
            float gf[4], cf[4];
#pragma unroll
            for (int q = 0; q < 4; ++q) { gf[q] = gsl[kk * 65 + r0 + q]; cf[q] = cul[kk * 65 + c0 + q]; }
#pragma unroll
            for (int q = 0; q < 4; ++q)
#pragma unroll
                for (int w2 = 0; w2 < 4; ++w2) acc[q][w2] += gf[q] * cf[w2];
        }
    }
#pragma unroll
    for (int q = 0; q < 4; ++q) {
        float4 pv = *(const float4*)&P[(j * 64 + r0 + q) * DD + bd * 64 + c0];
        float4 v = make_float4(pv.x - LRF * acc[q][0], pv.y - LRF * acc[q][1],
                               pv.z - LRF * acc[q][2], pv.w - LRF * acc[q][3]);
        *(float4*)&bv[(r0 + q) * DD + bd * 64 + c0] = v;
    }
}

// intra-chunk sequential scan; ONE block, 256 threads (thread = dims d, d+256)
__global__ __launch_bounds__(256) void tm_scan(const float* __restrict__ bv, const float* __restrict__ G,
                                               float* __restrict__ cu, int kchunk) {
    __shared__ float gl[64 * 64];   // intra-chunk Gram block (broadcast reads -> no conflicts)
    __shared__ float part[2][4];
    int tid = threadIdx.x;
    int wid = tid >> 6, lane = tid & 63;
    int p = kchunk >> 2, j = kchunk & 3;
    const float* Gp = G + p * 65536;
    for (int l = tid; l < 64 * 16; l += 256) {
        int r = l >> 4, c4 = (l & 15) * 4;
        float4 v = *(const float4*)&Gp[(j * 64 + r) * 256 + j * 64 + c4];
        *(float4*)&gl[r * 64 + c4] = v;
    }
    float acc0[64], acc1[64];
#pragma unroll
    for (int t = 0; t < 64; ++t) {
        acc0[t] = bv[t * DD + tid];
        acc1[t] = bv[t * DD + tid + 256];
    }
    __syncthreads();
    float* cup = cu + (p * 256 + j * 64) * DD;
#pragma unroll
    for (int s = 0; s < 64; ++s) {
        float u0 = acc0[s], u1 = acc1[s];
        float v = u0 * u0 + u1 * u1;
#pragma unroll
        for (int off = 32; off > 0; off >>= 1) v += __shfl_xor(v, off, 64);
        if (lane == 0) part[s & 1][wid] = v;
        __syncthreads();
        float n2u = part[s & 1][0] + part[s & 1][1] + part[s & 1][2] + part[s & 1][3];
        float n2 = n2u * gl[s * 64 + s];                      // ||u||^2 * ||a||^2
        float cs = (n2 > 0.25f) ? 0.5f * rsqrtf(n2) : 1.0f;  // min(1, CLIP/n)
        cup[s * DD + tid] = cs * u0;
        cup[s * DD + tid + 256] = cs * u1;
        float w0 = (LRF * cs) * u0, w1 = (LRF * cs) * u1;
        int t0 = s + 1;
#pragma unroll
        for (; t0 < 64 && (t0 & 3); ++t0) {
            float g = gl[s * 64 + t0];
            acc0[t0] -= g * w0; acc1[t0] -= g * w1;
        }
#pragma unroll
        for (; t0 < 64; t0 += 4) {
            float4 g4 = *(const float4*)&gl[s * 64 + t0];
            acc0[t0]     -= g4.x * w0; acc1[t0]     -= g4.x * w1;
            acc0[t0 + 1] -= g4.y * w0; acc1[t0 + 1] -= g4.y * w1;
            acc0[t0 + 2] -= g4.z * w0; acc1[t0 + 2] -= g4.z * w1;
            acc0[t0 + 3] -= g4.w * w0; acc1[t0 + 3] -= g4.w * w1;
        }
    }
}

// W += LR * sum_{r in sc p} cu_r (x) a_r  (rank-256); optional snapshot / final output
__global__ void tm_wupd(const float* __restrict__ a, const float* __restrict__ cu,
                        float* __restrict__ W, float* __restrict__ Wsnap,
                        const float* __restrict__ wb, float* __restrict__ outW,
                        int p, int snap_p, int is_final) {
    int idx = blockIdx.x * 256 + threadIdx.x;
    int i = idx >> 9, jj = idx & 511;
    const float* cb = cu + p * 256 * DD + i;
    const float* ab = a + p * 256 * DD + jj;
    float s = 0.f;
#pragma unroll 8
    for (int r = 0; r < 256; ++r) s += cb[r * DD] * ab[r * DD];
    float w = W[idx] + LRF * s;
    W[idx] = w;
    if (snap_p >= 0) Wsnap[snap_p * DD * DD + idx] = w;
    if (is_final) outW[idx] = w - wb[idx];
}

// ---------------- phase 3 (parallel output) ----------------

// out[b,t,:] = x[b,t,:] @ Wsnap[p].T   (64x64 tile GEMM, 4x4 micro)
__global__ __launch_bounds__(256) void tm_mem(const float* __restrict__ x, const float* __restrict__ Wsnap,
                                              float* __restrict__ out) {
    __shared__ float al[64 * 65];
    __shared__ float bl[64 * 65];
    int bid = blockIdx.x;
    int p = bid >> 8, rem = bid & 255, rt = rem >> 3, it = rem & 7;
    int tid = threadIdx.x;
    int c0 = (tid & 15) * 4, r0 = (tid >> 4) * 4;
    const float* Wp = Wsnap + p * DD * DD;
    float acc[4][4] = {};
    for (int kt = 0; kt < 8; ++kt) {
        if (kt) __syncthreads();
        for (int l = tid; l < 64 * 16; l += 256) {
            int r = l >> 4, c4 = (l & 15) * 4;
            int rloc = rt * 64 + r;
            int grow = ((rloc >> 8) * TT) + p * 256 + (rloc & 255);
            float4 v = *(const float4*)&x[grow * DD + kt * 64 + c4];
            al[r * 65 + c4] = v.x; al[r * 65 + c4 + 1] = v.y;
            al[r * 65 + c4 + 2] = v.z; al[r * 65 + c4 + 3] = v.w;
            float4 u = *(const float4*)&Wp[(it * 64 + r) * DD + kt * 64 + c4];
            bl[r * 65 + c4] = u.x; bl[r * 65 + c4 + 1] = u.y;
            bl[r * 65 + c4 + 2] = u.z; bl[r * 65 + c4 + 3] = u.w;
        }
        __syncthreads();
        for (int kk = 0; kk < 64; ++kk) {
            float af[4], bf[4];
#pragma unroll
            for (int q = 0; q < 4; ++q) { af[q] = al[(r0 + q) * 65 + kk]; bf[q] = bl[(c0 + q) * 65 + kk]; }
#pragma unroll
            for (int q = 0; q < 4; ++q)
#pragma unroll
                for (int w2 = 0; w2 < 4; ++w2) acc[q][w2] += af[q] * bf[w2];
        }
    }
#pragma unroll
    for (int q = 0; q < 4; ++q) {
        int rloc = rt * 64 + r0 + q;
        int grow = ((rloc >> 8) * TT) + p * 256 + (rloc & 255);
        float4 v = make_float4(acc[q][0], acc[q][1], acc[q][2], acc[q][3]);
        *(float4*)&out[grow * DD + it * 64 + c0] = v;
    }
}

// S[p][rloc][s] = x[row] . a[p*256+s]
__global__ __launch_bounds__(256) void tm_score(const float* __restrict__ x, const float* __restrict__ a,
                                                float* __restrict__ S) {
    __shared__ float al[64 * 65];
    __shared__ float bl[64 * 65];
    int bid = blockIdx.x;
    int st = bid & 3, rt = (bid >> 2) & 31, p = bid >> 7;
    int tid = threadIdx.x;
    int c0 = (tid & 15) * 4, r0 = (tid >> 4) * 4;
    float acc[4][4] = {};
    for (int kt = 0; kt < 8; ++kt) {
        if (kt) __syncthreads();
        for (int l = tid; l < 64 * 16; l += 256) {
            int r = l >> 4, c4 = (l & 15) * 4;
            int rloc = rt * 64 + r;
            int grow = ((rloc >> 8) * TT) + p * 256 + (rloc & 255);
            float4 v = *(const float4*)&x[grow * DD + kt * 64 + c4];
            al[r * 65 + c4] = v.x; al[r * 65 + c4 + 1] = v.y;
            al[r * 65 + c4 + 2] = v.z; al[r * 65 + c4 + 3] = v.w;
            float4 u = *(const float4*)&a[(p * 256 + st * 64 + r) * DD + kt * 64 + c4];
            bl[r * 65 + c4] = u.x; bl[r * 65 + c4 + 1] = u.y;
            bl[r * 65 + c4 + 2] = u.z; bl[r * 65 + c4 + 3] = u.w;
        }
        __syncthreads();
        for (int kk = 0; kk < 64; ++kk) {
            float af[4], bf[4];
#pragma unroll
            for (int q = 0; q < 4; ++q) { af[q] = al[(r0 + q) * 65 + kk]; bf[q] = bl[(c0 + q) * 65 + kk]; }
#pragma unroll
            for (int q = 0; q < 4; ++q)
#pragma unroll
                for (int w2 = 0; w2 < 4; ++w2) acc[q][w2] += af[q] * bf[w2];
        }
    }
#pragma unroll
    for (int q = 0; q < 4; ++q) {
        int rloc = rt * 64 + r0 + q;
        float4 v = make_float4(acc[q][0], acc[q][1], acc[q][2], acc[q][3]);
        *(float4*)&S[(p * 2048 + rloc) * 256 + st * 64 + c0] = v;
    }
}

// out[row][i] += LR * sum_{s<tloc} S[p][rloc][s] * cu[p*256+s][i]
__global__ __launch_bounds__(256) void tm_apply(const float* __restrict__ S, const float* __restrict__ cu,
                                                float* __restrict__ out) {
    __shared__ float al[64 * 65];
    __shared__ float bl[64 * 65];
    int bid = blockIdx.x;
    int it = bid & 7, rt = (bid >> 3) & 31, p = bid >> 8;
    int tid = threadIdx.x;
    int c0 = (tid & 15) * 4, r0 = (tid >> 4) * 4;
    float acc[4][4] = {};
    for (int kt = 0; kt < 4; ++kt) {
        if (kt) __syncthreads();
        for (int l = tid; l < 64 * 16; l += 256) {
            int r = l >> 4, c4 = (l & 15) * 4;
            int rloc = rt * 64 + r;
            int tq = rloc & 255;
            float4 v = *(const float4*)&S[(p * 2048 + rloc) * 256 + kt * 64 + c4];
            int sb = kt * 64 + c4;
            al[r * 65 + c4]     = (sb + 0 < tq) ? v.x : 0.f;
            al[r * 65 + c4 + 1] = (sb + 1 < tq) ? v.y : 0.f;
            al[r * 65 + c4 + 2] = (sb + 2 < tq) ? v.z : 0.f;
            al[r * 65 + c4 + 3] = (sb + 3 < tq) ? v.w : 0.f;
            float4 u = *(const float4*)&cu[(p * 256 + kt * 64 + r) * DD + it * 64 + c4];
            bl[r * 65 + c4] = u.x; bl[r * 65 + c4 + 1] = u.y;
            bl[r * 65 + c4 + 2] = u.z; bl[r * 65 + c4 + 3] = u.w;
        }
        __syncthreads();
        for (int kk = 0; kk < 64; ++kk) {
            float af[4], bf[4];
#pragma unroll
            for (int q = 0; q < 4; ++q) { af[q] = al[(r0 + q) * 65 + kk]; bf[q] = bl[kk * 65 + c0 + q]; }
#pragma unroll
            for (int q = 0; q < 4; ++q)
#pragma unroll
                for (int w2 = 0; w2 < 4; ++w2) acc[q][w2] += af[q] * bf[w2];
        }
    }
#pragma unroll
    for (int q = 0; q < 4; ++q) {
        int rloc = rt * 64 + r0 + q;
        int grow = ((rloc >> 8) * TT) + p * 256 + (rloc & 255);
        float4 cur = *(float4*)&out[grow * DD + it * 64 + c0];
        cur.x += LRF * acc[q][0]; cur.y += LRF * acc[q][1];
        cur.z += LRF * acc[q][2]; cur.w += LRF * acc[q][3];
        *(float4*)&out[grow * DD + it * 64 + c0] = cur;
    }
}

// out[row][i] *= sigmoid(x[row] . gate_w[i] + gate_b[i])
__global__ __launch_bounds__(256) void tm_gate(const float* __restrict__ x, const float* __restrict__ gw,
                                               const float* __restrict__ gb, float* __restrict__ out) {
    __shared__ float al[64 * 65];
    __shared__ float bl[64 * 65];
    int bid = blockIdx.x;
    int it = bid & 7, rt = bid >> 3;
    int tid = threadIdx.x;
    int c0 = (tid & 15) * 4, r0 = (tid >> 4) * 4;
    float acc[4][4] = {};
    for (int kt = 0; kt < 8; ++kt) {
        if (kt) __syncthreads();
        for (int l = tid; l < 64 * 16; l += 256) {
            int r = l >> 4, c4 = (l & 15) * 4;
            int grow = rt * 64 + r;
            float4 v = *(const float4*)&x[grow * DD + kt * 64 + c4];
            al[r * 65 + c4] = v.x; al[r * 65 + c4 + 1] = v.y;
            al[r * 65 + c4 + 2] = v.z; al[r * 65 + c4 + 3] = v.w;
            float4 u = *(const float4*)&gw[(it * 64 + r) * DD + kt * 64 + c4];
            bl[r * 65 + c4] = u.x; bl[r * 65 + c4 + 1] = u.y;
            bl[r * 65 + c4 + 2] = u.z; bl[r * 65 + c4 + 3] = u.w;
        }
        __syncthreads();
        for (int kk = 0; kk < 64; ++kk) {
            float af[4], bf[4];
#pragma unroll
            for (int q = 0; q < 4; ++q) { af[q] = al[(r0 + q) * 65 + kk]; bf[q] = bl[(c0 + q) * 65 + kk]; }
#pragma unroll
            for (int q = 0; q < 4; ++q)
#pragma unroll
                for (int w2 = 0; w2 < 4; ++w2) acc[q][w2] += af[q] * bf[w2];
        }
    }
#pragma unroll
    for (int q = 0; q < 4; ++q) {
        int grow = rt * 64 + r0 + q;
        float4 cur = *(float4*)&out[grow * DD + it * 64 + c0];
        float z0 = acc[q][0] + gb[it * 64 + c0 + 0];
        float z1 = acc[q][1] + gb[it * 64 + c0 + 1];
        float z2 = acc[q][2] + gb[it * 64 + c0 + 2];
        float z3 = acc[q][3] + gb[it * 64 + c0 + 3];
        cur.x *= 1.f / (1.f + expf(-z0));
        cur.y *= 1.f / (1.f + expf(-z1));
        cur.z *= 1.f / (1.f + expf(-z2));
        cur.w *= 1.f / (1.f + expf(-z3));
        *(float4*)&out[grow * DD + it * 64 + c0] = cur;
    }
}

extern "C" void kernel_launch(void* const* d_in, const int* in_sizes, int n_in,
                              void* d_out, int out_size, void* d_ws, size_t ws_size,
                              hipStream_t stream) {
    const float* x   = (const float*)d_in[0];
    const float* Wc0 = (const float*)d_in[1];
    const float* Wb  = (const float*)d_in[2];
    const float* gw  = (const float*)d_in[3];
    const float* gb  = (const float*)d_in[4];
    float* out  = (float*)d_out;
    float* outW = out + BB * TT * DD;   // 16777216

    float* ws = (float*)d_ws;
    float* A  = ws + OFF_A;
    float* CU = ws + OFF_CU;
    float* G  = ws + OFF_G;
    float* P  = ws + OFF_P;
    float* BV = ws + OFF_BV;
    float* W  = ws + OFF_W;
    float* WS = ws + OFF_WS;
    float* S  = ws + OFF_S;

    tm_mean<<<(TT * DD) / 256, 256, 0, stream>>>(x, A);
    tm_init<<<(DD * DD) / 256, 256, 0, stream>>>(Wb, Wc0, W, WS);
    tm_gram<<<256, 256, 0, stream>>>(A, G);
    tm_P<<<32, 256, 0, stream>>>(A, W, P, 0);

    for (int p = 0; p < 16; ++p) {
        for (int j = 0; j < 4; ++j) {
            tm_corr<<<8, 256, 0, stream>>>(P, G, CU, BV, p, j);
            tm_scan<<<1, 256, 0, stream>>>(BV, G, CU, p * 4 + j);
        }
        if (p < 15) {
            tm_wupd<<<(DD * DD) / 256, 256, 0, stream>>>(A, CU, W, WS, Wb, outW, p, p + 1, 0);
            tm_P<<<32, 256, 0, stream>>>(A, W, P, p + 1);
        }
    }
    tm_wupd<<<(DD * DD) / 256, 256, 0, stream>>>(A, CU, W, WS, Wb, outW, 15, -1, 1);

    tm_mem<<<16 * 256, 256, 0, stream>>>(x, WS, out);
    tm_score<<<16 * 128, 256, 0, stream>>>(x, A, S);
    tm_apply<<<16 * 256, 256, 0, stream>>>(S, CU, out);
    tm_gate<<<512 * 8, 256, 0, stream>>>(x, gw, gb, out);
}